// Round 5
// baseline (617.452 us; speedup 1.0000x reference)
//
#include <hip/hip_runtime.h>
#include <hip/hip_bf16.h>
#include <stdint.h>

#define D    256   // hidden dim
#define K2   512   // 2*D (GEMM K, q_star width)
#define G4   1024  // 4*D (gate count)
#define RPS  8     // rows per wave per step (8 KB in flight per wave)

typedef __attribute__((ext_vector_type(8))) short  short8;
typedef __attribute__((ext_vector_type(4))) float  float4v;

__device__ inline short f2bf(float v) {
    __hip_bfloat16 b = __float2bfloat16(v);
    union { __hip_bfloat16 b; unsigned short u; } cv; cv.b = b;
    return (short)cv.u;
}
__device__ inline float bfs2f(short s) {
    union { unsigned int i; float f; } v;
    v.i = ((unsigned int)(unsigned short)s) << 16;
    return v.f;
}

// ---- per-graph boundaries: start[g] = first node with seg >= g --------------
__global__ void k_bounds(const int* __restrict__ seg, int N, int B,
                         int* __restrict__ start) {
    int g = blockIdx.x * blockDim.x + threadIdx.x;
    if (g > B) return;
    int lo = 0, hi = N;
    while (lo < hi) { int mid = (lo + hi) >> 1; if (seg[mid] < g) lo = mid + 1; else hi = mid; }
    start[g] = lo;
}

// ---- Wc = [W_ih[:, :D] + W_hh | W_ih[:, D:2D]] split into bf16 hi+lo --------
__global__ void k_prep(const float* __restrict__ Wih,
                       const float* __restrict__ Whh,
                       const float* __restrict__ bih,
                       const float* __restrict__ bhh,
                       short* __restrict__ Wch, short* __restrict__ Wcl,
                       float* __restrict__ bsum) {
    int idx = blockIdx.x * blockDim.x + threadIdx.x;
    if (idx >= G4 * K2) return;
    int r = idx >> 9, cc = idx & (K2 - 1);
    float v = Wih[idx];
    if (cc < D) v += Whh[r * D + cc];
    short hi = f2bf(v);
    Wch[idx] = hi;
    Wcl[idx] = f2bf(v - bfs2f(hi));
    if (idx < G4) bsum[idx] = bih[idx] + bhh[idx];
}

// ---- fused gates GEMM + LSTM pointwise --------------------------------------
// grid (B/16, 4), 256 thr. Wave w of block (bm,cg) owns m-rows [bm*16,+16) and
// hidden dims j in [cg*64 + w*16, +16), computing all 4 gate groups (rows
// j + g*256 of Wc) so the pointwise stays in registers. A (=X, fp32) is
// converted to bf16 hi/lo on the fly; A.B ~ Ah.Bh + Al.Bh + Ah.Bl (~fp22).
__global__ __launch_bounds__(256) void k_gemm_lstm(
        const float* __restrict__ X,
        const short* __restrict__ Wch, const short* __restrict__ Wcl,
        const float* __restrict__ bsum,
        float* __restrict__ c, float* __restrict__ h) {
    int wave = threadIdx.x >> 6, lane = threadIdx.x & 63;
    int row = lane & 15, quad = lane >> 4;
    int m0 = blockIdx.x * 16;
    int jbase = blockIdx.y * 64 + wave * 16;
    const float* pa  = X   + (size_t)(m0 + row) * K2 + quad * 8;
    const short* pbh = Wch + (size_t)(jbase + row) * K2 + quad * 8;
    const short* pbl = Wcl + (size_t)(jbase + row) * K2 + quad * 8;
    float4v acc0 = {0,0,0,0}, acc1 = {0,0,0,0}, acc2 = {0,0,0,0}, acc3 = {0,0,0,0};
#pragma unroll
    for (int k = 0; k < K2; k += 32) {
        float4v af0 = *(const float4v*)(pa + k);
        float4v af1 = *(const float4v*)(pa + k + 4);
        short8 ahi, alo;
#pragma unroll
        for (int q = 0; q < 4; q++) {
            float v = af0[q];
            short hi = f2bf(v);
            ahi[q] = hi; alo[q] = f2bf(v - bfs2f(hi));
        }
#pragma unroll
        for (int q = 0; q < 4; q++) {
            float v = af1[q];
            short hi = f2bf(v);
            ahi[q + 4] = hi; alo[q + 4] = f2bf(v - bfs2f(hi));
        }
#define GATE_MFMA(ACC, OFF)                                                        \
        {                                                                          \
            short8 bh = *(const short8*)(pbh + (size_t)(OFF) * K2 + k);            \
            short8 bl = *(const short8*)(pbl + (size_t)(OFF) * K2 + k);            \
            ACC = __builtin_amdgcn_mfma_f32_16x16x32_bf16(ahi, bh, ACC, 0, 0, 0);  \
            ACC = __builtin_amdgcn_mfma_f32_16x16x32_bf16(alo, bh, ACC, 0, 0, 0);  \
            ACC = __builtin_amdgcn_mfma_f32_16x16x32_bf16(ahi, bl, ACC, 0, 0, 0);  \
        }
        GATE_MFMA(acc0, 0)
        GATE_MFMA(acc1, 256)
        GATE_MFMA(acc2, 512)
        GATE_MFMA(acc3, 768)
#undef GATE_MFMA
    }
    // C/D layout: col = lane&15 (N dim = j), row = quad*4 + i (M dim = batch)
    int j = jbase + (lane & 15);
    float bi = bsum[j], bf_ = bsum[j + 256], bg = bsum[j + 512], bo = bsum[j + 768];
#pragma unroll
    for (int i = 0; i < 4; i++) {
        int m = m0 + quad * 4 + i;
        size_t ix = (size_t)m * D + j;
        float gi = acc0[i] + bi, gf = acc1[i] + bf_, gg = acc2[i] + bg, go = acc3[i] + bo;
        float si = 1.f / (1.f + __expf(-gi));
        float sf = 1.f / (1.f + __expf(-gf));
        float so = 1.f / (1.f + __expf(-go));
        float cn = sf * c[ix] + si * tanhf(gg);
        float hn = so * tanhf(cn);
        c[ix] = cn;
        h[ix] = hn;
    }
}

// ---- attention, single pass, online softmax, software-prefetched ------------
// Block g handles graph g. Wave w processes rows w*8.., stride 32, 8 rows per
// step with the NEXT step's 8 loads issued before the current reduction chain
// (keeps ~8 KB per wave in flight continuously). Lane owns dims lane*4..+3.
__global__ __launch_bounds__(256, 4) void k_attn(const float* __restrict__ feat,
                                                 const int* __restrict__ start,
                                                 const float* __restrict__ h,
                                                 float* __restrict__ X, int N) {
    __shared__ float accs[4 * D];
    __shared__ float ms[4], ls[4];
    int g = blockIdx.x;
    int t = threadIdx.x;
    int lane = t & 63, wave = t >> 6;
    // publish h into X row g (block g owns row g -> race-free)
    float hv = h[(size_t)g * D + t];
    X[(size_t)g * K2 + t] = hv;
    int s = start[g], e = start[g + 1];
    s = max(0, min(s, N)); e = max(s, min(e, N));   // defensive clamp
    int cnt = e - s;
    if (cnt <= 0) {                                  // block-uniform
        X[(size_t)g * K2 + D + t] = 0.f;
        return;
    }
    const float NEG = -3.0e38f;
    float4v q = *(const float4v*)(h + (size_t)g * D + lane * 4);
    float m = NEG, l = 0.f;
    float4v acc = {0.f, 0.f, 0.f, 0.f};

    int base = wave * RPS;
    float4v rows[RPS];
    // prefetch step 0 (addresses clamped -> always in-bounds)
#pragma unroll
    for (int r = 0; r < RPS; r++) {
        int idx = base + r;
        int ci = (idx < cnt) ? (s + idx) : s;
        rows[r] = *((const float4v*)(feat + (size_t)ci * D) + lane);
    }
    for (int n0 = base; n0 < cnt; n0 += 4 * RPS) {
        float4v cur[RPS];
#pragma unroll
        for (int r = 0; r < RPS; r++) cur[r] = rows[r];
        // prefetch next step before the reduction chain
        int nn = n0 + 4 * RPS;
#pragma unroll
        for (int r = 0; r < RPS; r++) {
            int idx = nn + r;
            int ci = (idx < cnt) ? (s + idx) : s;
            rows[r] = *((const float4v*)(feat + (size_t)ci * D) + lane);
        }
        // dots
        float ev[RPS];
#pragma unroll
        for (int r = 0; r < RPS; r++)
            ev[r] = cur[r].x * q.x + cur[r].y * q.y + cur[r].z * q.z + cur[r].w * q.w;
        // butterfly reduce all 8 rows (ILP-8 on the 6-step chain)
#pragma unroll
        for (int step = 1; step < 64; step <<= 1) {
#pragma unroll
            for (int r = 0; r < RPS; r++) ev[r] += __shfl_xor(ev[r], step, 64);
        }
        float mnew = m;
#pragma unroll
        for (int r = 0; r < RPS; r++) {
            if (n0 + r >= cnt) ev[r] = NEG;
            mnew = fmaxf(mnew, ev[r]);
        }
        float alpha = __expf(m - mnew);               // m=NEG,l=0 first time: ok
        float w[RPS];
        float wsum = 0.f;
#pragma unroll
        for (int r = 0; r < RPS; r++) {
            w[r] = (n0 + r < cnt) ? __expf(ev[r] - mnew) : 0.f;
            wsum += w[r];
        }
        l = l * alpha + wsum;
        acc.x *= alpha; acc.y *= alpha; acc.z *= alpha; acc.w *= alpha;
#pragma unroll
        for (int r = 0; r < RPS; r++) {
            acc.x += w[r] * cur[r].x;
            acc.y += w[r] * cur[r].y;
            acc.z += w[r] * cur[r].z;
            acc.w += w[r] * cur[r].w;
        }
        m = mnew;
    }

    // merge 4 waves via LDS
    *((float4v*)(accs + wave * D + lane * 4)) = acc;
    if (lane == 0) { ms[wave] = m; ls[wave] = l; }
    __syncthreads();
    float mt = fmaxf(fmaxf(ms[0], ms[1]), fmaxf(ms[2], ms[3]));
    float s0 = __expf(ms[0] - mt), s1 = __expf(ms[1] - mt);
    float s2 = __expf(ms[2] - mt), s3 = __expf(ms[3] - mt);
    float lt = ls[0] * s0 + ls[1] * s1 + ls[2] * s2 + ls[3] * s3;
    float val = accs[t] * s0 + accs[D + t] * s1 + accs[2 * D + t] * s2 + accs[3 * D + t] * s3;
    X[(size_t)g * K2 + D + t] = val / lt;
}

extern "C" void kernel_launch(void* const* d_in, const int* in_sizes, int n_in,
                              void* d_out, int out_size, void* d_ws, size_t ws_size,
                              hipStream_t stream) {
    const float* feat = (const float*)d_in[0];
    const float* Wih  = (const float*)d_in[1];
    const float* Whh  = (const float*)d_in[2];
    const float* bih  = (const float*)d_in[3];
    const float* bhh  = (const float*)d_in[4];
    const int*   seg  = (const int*)d_in[5];
    const int N = in_sizes[5];
    const int B = out_size / K2;   // 1024

    // ws layout (~4.01 MB): c | h | Wch | Wcl | bsum | start
    char* ws = (char*)d_ws;
    size_t szC = (size_t)B * D * sizeof(float);            // 1 MB
    float* c   = (float*)ws;
    float* h   = (float*)(ws + szC);
    short* Wch = (short*)(ws + 2 * szC);                   // 1 MB
    short* Wcl = (short*)(ws + 2 * szC + (size_t)G4 * K2 * sizeof(short));
    float* bsum = (float*)(ws + 2 * szC + 2 * (size_t)G4 * K2 * sizeof(short));
    int*   start = (int*)((char*)bsum + (size_t)G4 * sizeof(float));

    float* X = (float*)d_out;                              // q_star [B, 2D] fp32

    hipMemsetAsync(ws, 0, 2 * szC, stream);                              // c, h = 0
    hipMemsetAsync(d_out, 0, (size_t)B * K2 * sizeof(float), stream);    // X = 0
    k_prep<<<(G4 * K2 + 255) / 256, 256, 0, stream>>>(Wih, Whh, bih, bhh, Wch, Wcl, bsum);
    k_bounds<<<(B + 1 + 255) / 256, 256, 0, stream>>>(seg, N, B, start);

    for (int it = 0; it < 6; it++) {
        k_gemm_lstm<<<dim3(B / 16, 4), 256, 0, stream>>>(X, Wch, Wcl, bsum, c, h);
        k_attn<<<B, 256, 0, stream>>>(feat, start, h, X, N);
    }
}

// Round 6
// 587.648 us; speedup vs baseline: 1.0507x; 1.0507x over previous
//
#include <hip/hip_runtime.h>
#include <hip/hip_bf16.h>
#include <hip/hip_fp16.h>
#include <stdint.h>

#define D    256   // hidden dim
#define K2   512   // 2*D (GEMM K, q_star width)
#define G4   1024  // 4*D (gate count)

typedef __attribute__((ext_vector_type(8))) short  short8;
typedef __attribute__((ext_vector_type(4))) float  float4v;

__device__ inline short f2bf(float v) {
    __hip_bfloat16 b = __float2bfloat16(v);
    union { __hip_bfloat16 b; unsigned short u; } cv; cv.b = b;
    return (short)cv.u;
}
__device__ inline float bfs2f(short s) {
    union { unsigned int i; float f; } v;
    v.i = ((unsigned int)(unsigned short)s) << 16;
    return v.f;
}

// ---- per-graph boundaries: start[g] = first node with seg >= g --------------
__global__ void k_bounds(const int* __restrict__ seg, int N, int B,
                         int* __restrict__ start) {
    int g = blockIdx.x * blockDim.x + threadIdx.x;
    if (g > B) return;
    int lo = 0, hi = N;
    while (lo < hi) { int mid = (lo + hi) >> 1; if (seg[mid] < g) lo = mid + 1; else hi = mid; }
    start[g] = lo;
}

// ---- feat fp32 -> fp16 (one-time; halves per-iteration attention traffic) ---
__global__ void k_cvt(const float* __restrict__ feat, __half* __restrict__ feat16,
                      int total) {
    int i = (blockIdx.x * blockDim.x + threadIdx.x) * 8;
    int stride = gridDim.x * blockDim.x * 8;
    for (; i < total; i += stride) {
        float4v a = *(const float4v*)(feat + i);
        float4v b = *(const float4v*)(feat + i + 4);
        union { __half2 h2[4]; uint4 u; } o;
        o.h2[0] = __floats2half2_rn(a.x, a.y);
        o.h2[1] = __floats2half2_rn(a.z, a.w);
        o.h2[2] = __floats2half2_rn(b.x, b.y);
        o.h2[3] = __floats2half2_rn(b.z, b.w);
        *(uint4*)(feat16 + i) = o.u;
    }
}

// ---- Wc = [W_ih[:, :D] + W_hh | W_ih[:, D:2D]] split into bf16 hi+lo --------
__global__ void k_prep(const float* __restrict__ Wih,
                       const float* __restrict__ Whh,
                       const float* __restrict__ bih,
                       const float* __restrict__ bhh,
                       short* __restrict__ Wch, short* __restrict__ Wcl,
                       float* __restrict__ bsum) {
    int idx = blockIdx.x * blockDim.x + threadIdx.x;
    if (idx >= G4 * K2) return;
    int r = idx >> 9, cc = idx & (K2 - 1);
    float v = Wih[idx];
    if (cc < D) v += Whh[r * D + cc];
    short hi = f2bf(v);
    Wch[idx] = hi;
    Wcl[idx] = f2bf(v - bfs2f(hi));
    if (idx < G4) bsum[idx] = bih[idx] + bhh[idx];
}

// ---- fused gates GEMM + LSTM pointwise --------------------------------------
__global__ __launch_bounds__(256) void k_gemm_lstm(
        const float* __restrict__ X,
        const short* __restrict__ Wch, const short* __restrict__ Wcl,
        const float* __restrict__ bsum,
        float* __restrict__ c, float* __restrict__ h) {
    int wave = threadIdx.x >> 6, lane = threadIdx.x & 63;
    int row = lane & 15, quad = lane >> 4;
    int m0 = blockIdx.x * 16;
    int jbase = blockIdx.y * 64 + wave * 16;
    const float* pa  = X   + (size_t)(m0 + row) * K2 + quad * 8;
    const short* pbh = Wch + (size_t)(jbase + row) * K2 + quad * 8;
    const short* pbl = Wcl + (size_t)(jbase + row) * K2 + quad * 8;
    float4v acc0 = {0,0,0,0}, acc1 = {0,0,0,0}, acc2 = {0,0,0,0}, acc3 = {0,0,0,0};
#pragma unroll
    for (int k = 0; k < K2; k += 32) {
        float4v af0 = *(const float4v*)(pa + k);
        float4v af1 = *(const float4v*)(pa + k + 4);
        short8 ahi, alo;
#pragma unroll
        for (int q = 0; q < 4; q++) {
            float v = af0[q];
            short hi = f2bf(v);
            ahi[q] = hi; alo[q] = f2bf(v - bfs2f(hi));
        }
#pragma unroll
        for (int q = 0; q < 4; q++) {
            float v = af1[q];
            short hi = f2bf(v);
            ahi[q + 4] = hi; alo[q + 4] = f2bf(v - bfs2f(hi));
        }
#define GATE_MFMA(ACC, OFF)                                                        \
        {                                                                          \
            short8 bh = *(const short8*)(pbh + (size_t)(OFF) * K2 + k);            \
            short8 bl = *(const short8*)(pbl + (size_t)(OFF) * K2 + k);            \
            ACC = __builtin_amdgcn_mfma_f32_16x16x32_bf16(ahi, bh, ACC, 0, 0, 0);  \
            ACC = __builtin_amdgcn_mfma_f32_16x16x32_bf16(alo, bh, ACC, 0, 0, 0);  \
            ACC = __builtin_amdgcn_mfma_f32_16x16x32_bf16(ahi, bl, ACC, 0, 0, 0);  \
        }
        GATE_MFMA(acc0, 0)
        GATE_MFMA(acc1, 256)
        GATE_MFMA(acc2, 512)
        GATE_MFMA(acc3, 768)
#undef GATE_MFMA
    }
    int j = jbase + (lane & 15);
    float bi = bsum[j], bf_ = bsum[j + 256], bg = bsum[j + 512], bo = bsum[j + 768];
#pragma unroll
    for (int i = 0; i < 4; i++) {
        int m = m0 + quad * 4 + i;
        size_t ix = (size_t)m * D + j;
        float gi = acc0[i] + bi, gf = acc1[i] + bf_, gg = acc2[i] + bg, go = acc3[i] + bo;
        float si = 1.f / (1.f + __expf(-gi));
        float sf = 1.f / (1.f + __expf(-gf));
        float so = 1.f / (1.f + __expf(-go));
        float cn = sf * c[ix] + si * tanhf(gg);
        float hn = so * tanhf(cn);
        c[ix] = cn;
        h[ix] = hn;
    }
}

// ---- attention, single pass over fp16 feat, online softmax ------------------
// Block g = graph g. Wave w handles rows w*4.., stride 16, 4 rows/step.
// Lane owns dims lane*4..+3 (its uint2 = 4 halves). Waves merge via LDS.
__global__ __launch_bounds__(256) void k_attn(const __half* __restrict__ feat16,
                                              const int* __restrict__ start,
                                              const float* __restrict__ h,
                                              float* __restrict__ X, int N) {
    __shared__ float accs[4 * D];
    __shared__ float ms[4], ls[4];
    int g = blockIdx.x;
    int t = threadIdx.x;
    int lane = t & 63, wave = t >> 6;
    float hv = h[(size_t)g * D + t];
    X[(size_t)g * K2 + t] = hv;                       // publish h (row g owned)
    int s = start[g], e = start[g + 1];
    s = max(0, min(s, N)); e = max(s, min(e, N));
    int cnt = e - s;
    if (cnt <= 0) {
        X[(size_t)g * K2 + D + t] = 0.f;
        return;
    }
    const float NEG = -3.0e38f;
    float4v q = *(const float4v*)(h + (size_t)g * D + lane * 4);
    float m = NEG, l = 0.f;
    float4v acc = {0.f, 0.f, 0.f, 0.f};

    for (int n0 = wave * 4; n0 < cnt; n0 += 16) {
        uint2 raw[4];
#pragma unroll
        for (int r = 0; r < 4; r++) {
            int idx = n0 + r;
            int ci = (idx < cnt) ? (s + idx) : s;     // clamp: no OOB read
            raw[r] = *((const uint2*)(feat16 + (size_t)ci * D) + lane);
        }
        float4v rows[4];
        float ev[4];
#pragma unroll
        for (int r = 0; r < 4; r++) {
            union { uint2 u; __half2 h2[2]; } cv; cv.u = raw[r];
            float2 f01 = __half22float2(cv.h2[0]);
            float2 f23 = __half22float2(cv.h2[1]);
            rows[r].x = f01.x; rows[r].y = f01.y; rows[r].z = f23.x; rows[r].w = f23.y;
            ev[r] = rows[r].x * q.x + rows[r].y * q.y + rows[r].z * q.z + rows[r].w * q.w;
        }
#pragma unroll
        for (int step = 1; step < 64; step <<= 1) {
#pragma unroll
            for (int r = 0; r < 4; r++) ev[r] += __shfl_xor(ev[r], step, 64);
        }
        float mnew = m;
#pragma unroll
        for (int r = 0; r < 4; r++) {
            if (n0 + r >= cnt) ev[r] = NEG;
            mnew = fmaxf(mnew, ev[r]);
        }
        float alpha = __expf(m - mnew);
        float w[4];
        float wsum = 0.f;
#pragma unroll
        for (int r = 0; r < 4; r++) {
            w[r] = (n0 + r < cnt) ? __expf(ev[r] - mnew) : 0.f;
            wsum += w[r];
        }
        l = l * alpha + wsum;
        acc.x *= alpha; acc.y *= alpha; acc.z *= alpha; acc.w *= alpha;
#pragma unroll
        for (int r = 0; r < 4; r++) {
            acc.x += w[r] * rows[r].x;
            acc.y += w[r] * rows[r].y;
            acc.z += w[r] * rows[r].z;
            acc.w += w[r] * rows[r].w;
        }
        m = mnew;
    }

    // merge 4 waves via LDS
    *((float4v*)(accs + wave * D + lane * 4)) = acc;
    if (lane == 0) { ms[wave] = m; ls[wave] = l; }
    __syncthreads();
    float mt = fmaxf(fmaxf(ms[0], ms[1]), fmaxf(ms[2], ms[3]));
    float s0 = __expf(ms[0] - mt), s1 = __expf(ms[1] - mt);
    float s2 = __expf(ms[2] - mt), s3 = __expf(ms[3] - mt);
    float lt = ls[0] * s0 + ls[1] * s1 + ls[2] * s2 + ls[3] * s3;
    float val = accs[t] * s0 + accs[D + t] * s1 + accs[2 * D + t] * s2 + accs[3 * D + t] * s3;
    X[(size_t)g * K2 + D + t] = val / lt;
}

extern "C" void kernel_launch(void* const* d_in, const int* in_sizes, int n_in,
                              void* d_out, int out_size, void* d_ws, size_t ws_size,
                              hipStream_t stream) {
    const float* feat = (const float*)d_in[0];
    const float* Wih  = (const float*)d_in[1];
    const float* Whh  = (const float*)d_in[2];
    const float* bih  = (const float*)d_in[3];
    const float* bhh  = (const float*)d_in[4];
    const int*   seg  = (const int*)d_in[5];
    const int N = in_sizes[5];
    const int B = out_size / K2;   // 1024
    const int total = N * D;       // 51.2M, multiple of 8

    // ws layout: [c 1MB | h 1MB | Wch 1MB | Wcl 1MB | bsum 4KB | start 4KB]
    // then feat16 at 16MB offset (102.4 MB)
    char* ws = (char*)d_ws;
    size_t szC = (size_t)B * D * sizeof(float);
    float* c   = (float*)ws;
    float* h   = (float*)(ws + szC);
    short* Wch = (short*)(ws + 2 * szC);
    short* Wcl = (short*)(ws + 2 * szC + (size_t)G4 * K2 * sizeof(short));
    float* bsum = (float*)(ws + 2 * szC + 2 * (size_t)G4 * K2 * sizeof(short));
    int*   start = (int*)((char*)bsum + (size_t)G4 * sizeof(float));
    __half* feat16 = (__half*)(ws + (size_t)16 * 1024 * 1024);

    float* X = (float*)d_out;      // q_star [B, 2D] fp32

    hipMemsetAsync(ws, 0, 2 * szC, stream);                              // c, h = 0
    hipMemsetAsync(d_out, 0, (size_t)B * K2 * sizeof(float), stream);    // X = 0
    k_cvt<<<8192, 256, 0, stream>>>(feat, feat16, total);
    k_prep<<<(G4 * K2 + 255) / 256, 256, 0, stream>>>(Wih, Whh, bih, bhh, Wch, Wcl, bsum);
    k_bounds<<<(B + 1 + 255) / 256, 256, 0, stream>>>(seg, N, B, start);

    for (int it = 0; it < 6; it++) {
        k_gemm_lstm<<<dim3(B / 16, 4), 256, 0, stream>>>(X, Wch, Wcl, bsum, c, h);
        k_attn<<<B, 256, 0, stream>>>(feat16, start, h, X, N);
    }
}

// Round 7
// 565.359 us; speedup vs baseline: 1.0921x; 1.0394x over previous
//
#include <hip/hip_runtime.h>
#include <hip/hip_bf16.h>
#include <hip/hip_fp16.h>
#include <stdint.h>

#define D    256   // hidden dim
#define K2   512   // 2*D (GEMM K, q_star width)
#define G4   1024  // 4*D (gate count)

typedef __attribute__((ext_vector_type(8))) short  short8;
typedef __attribute__((ext_vector_type(4))) float  float4v;

__device__ inline short f2bf(float v) {
    __hip_bfloat16 b = __float2bfloat16(v);
    union { __hip_bfloat16 b; unsigned short u; } cv; cv.b = b;
    return (short)cv.u;
}
__device__ inline float bfs2f(short s) {
    union { unsigned int i; float f; } v;
    v.i = ((unsigned int)(unsigned short)s) << 16;
    return v.f;
}

// ---- wave64 sum via DPP (VALU pipe only — no ds_bpermute) -------------------
// Hillis-Steele within each row16 (shr 1,2,4,8), then bcast15 (rows 1,3) and
// bcast31 (rows 2,3): lane 63 holds the full 64-lane sum; readlane broadcasts.
__device__ inline float wave_sum64(float x) {
    union { float f; int i; } c, t;
#define DPP_ADD(CTRL, RM)                                                     \
    c.f = x;                                                                  \
    t.i = __builtin_amdgcn_update_dpp(0, c.i, (CTRL), (RM), 0xf, true);       \
    x += t.f;
    DPP_ADD(0x111, 0xf)   // row_shr:1
    DPP_ADD(0x112, 0xf)   // row_shr:2
    DPP_ADD(0x114, 0xf)   // row_shr:4
    DPP_ADD(0x118, 0xf)   // row_shr:8
    DPP_ADD(0x142, 0xa)   // row_bcast:15 -> rows 1,3
    DPP_ADD(0x143, 0xc)   // row_bcast:31 -> rows 2,3
#undef DPP_ADD
    union { float f; int i; } r; r.f = x;
    r.i = __builtin_amdgcn_readlane(r.i, 63);
    return r.f;
}

// ---- per-graph boundaries: start[g] = first node with seg >= g --------------
__global__ void k_bounds(const int* __restrict__ seg, int N, int B,
                         int* __restrict__ start) {
    int g = blockIdx.x * blockDim.x + threadIdx.x;
    if (g > B) return;
    int lo = 0, hi = N;
    while (lo < hi) { int mid = (lo + hi) >> 1; if (seg[mid] < g) lo = mid + 1; else hi = mid; }
    start[g] = lo;
}

// ---- feat fp32 -> fp16 (one-time; halves per-iteration attention traffic) ---
__global__ void k_cvt(const float* __restrict__ feat, __half* __restrict__ feat16,
                      int total) {
    int i = (blockIdx.x * blockDim.x + threadIdx.x) * 8;
    int stride = gridDim.x * blockDim.x * 8;
    for (; i < total; i += stride) {
        float4v a = *(const float4v*)(feat + i);
        float4v b = *(const float4v*)(feat + i + 4);
        union { __half2 h2[4]; uint4 u; } o;
        o.h2[0] = __floats2half2_rn(a.x, a.y);
        o.h2[1] = __floats2half2_rn(a.z, a.w);
        o.h2[2] = __floats2half2_rn(b.x, b.y);
        o.h2[3] = __floats2half2_rn(b.z, b.w);
        *(uint4*)(feat16 + i) = o.u;
    }
}

// ---- Wc = [W_ih[:, :D] + W_hh | W_ih[:, D:2D]] split into bf16 hi+lo --------
__global__ void k_prep(const float* __restrict__ Wih,
                       const float* __restrict__ Whh,
                       const float* __restrict__ bih,
                       const float* __restrict__ bhh,
                       short* __restrict__ Wch, short* __restrict__ Wcl,
                       float* __restrict__ bsum) {
    int idx = blockIdx.x * blockDim.x + threadIdx.x;
    if (idx >= G4 * K2) return;
    int r = idx >> 9, cc = idx & (K2 - 1);
    float v = Wih[idx];
    if (cc < D) v += Whh[r * D + cc];
    short hi = f2bf(v);
    Wch[idx] = hi;
    Wcl[idx] = f2bf(v - bfs2f(hi));
    if (idx < G4) bsum[idx] = bih[idx] + bhh[idx];
}

// ---- fused gates GEMM + LSTM pointwise --------------------------------------
// A operand (q_star) arrives PRE-SPLIT as bf16 hi/lo (Xh/Xl, written by k_attn)
// so the k-loop is pure loads + MFMA. A.B ~ Ah.Bh + Al.Bh + Ah.Bl (~fp22).
__global__ __launch_bounds__(256) void k_gemm_lstm(
        const short* __restrict__ Xh, const short* __restrict__ Xl,
        const short* __restrict__ Wch, const short* __restrict__ Wcl,
        const float* __restrict__ bsum,
        float* __restrict__ c, float* __restrict__ h) {
    int wave = threadIdx.x >> 6, lane = threadIdx.x & 63;
    int row = lane & 15, quad = lane >> 4;
    int m0 = blockIdx.x * 16;
    int jbase = blockIdx.y * 64 + wave * 16;
    const short* pah = Xh  + (size_t)(m0 + row) * K2 + quad * 8;
    const short* pal = Xl  + (size_t)(m0 + row) * K2 + quad * 8;
    const short* pbh = Wch + (size_t)(jbase + row) * K2 + quad * 8;
    const short* pbl = Wcl + (size_t)(jbase + row) * K2 + quad * 8;
    float4v acc0 = {0,0,0,0}, acc1 = {0,0,0,0}, acc2 = {0,0,0,0}, acc3 = {0,0,0,0};
#pragma unroll
    for (int k = 0; k < K2; k += 32) {
        short8 ahi = *(const short8*)(pah + k);
        short8 alo = *(const short8*)(pal + k);
#define GATE_MFMA(ACC, OFF)                                                        \
        {                                                                          \
            short8 bh = *(const short8*)(pbh + (size_t)(OFF) * K2 + k);            \
            short8 bl = *(const short8*)(pbl + (size_t)(OFF) * K2 + k);            \
            ACC = __builtin_amdgcn_mfma_f32_16x16x32_bf16(ahi, bh, ACC, 0, 0, 0);  \
            ACC = __builtin_amdgcn_mfma_f32_16x16x32_bf16(alo, bh, ACC, 0, 0, 0);  \
            ACC = __builtin_amdgcn_mfma_f32_16x16x32_bf16(ahi, bl, ACC, 0, 0, 0);  \
        }
        GATE_MFMA(acc0, 0)
        GATE_MFMA(acc1, 256)
        GATE_MFMA(acc2, 512)
        GATE_MFMA(acc3, 768)
#undef GATE_MFMA
    }
    // C/D layout: col = lane&15 (N dim = j), row = quad*4 + i (M dim = batch)
    int j = jbase + (lane & 15);
    float bi = bsum[j], bf_ = bsum[j + 256], bg = bsum[j + 512], bo = bsum[j + 768];
#pragma unroll
    for (int i = 0; i < 4; i++) {
        int m = m0 + quad * 4 + i;
        size_t ix = (size_t)m * D + j;
        float gi = acc0[i] + bi, gf = acc1[i] + bf_, gg = acc2[i] + bg, go = acc3[i] + bo;
        float si = 1.f / (1.f + __expf(-gi));
        float sf = 1.f / (1.f + __expf(-gf));
        float so = 1.f / (1.f + __expf(-go));
        float cn = sf * c[ix] + si * tanhf(gg);
        float hn = so * tanhf(cn);
        c[ix] = cn;
        h[ix] = hn;
    }
}

// ---- attention, single pass over fp16 feat, online softmax, DPP reduce ------
// Block g = graph g. Wave w handles rows w*4.., stride 16, 4 rows/step.
// Lane owns dims lane*4..+3 (its uint2 = 4 halves). Waves merge via LDS once.
// Publishes q_star row g as fp32 (d_out) AND pre-split bf16 hi/lo (Xh/Xl).
__global__ __launch_bounds__(256) void k_attn(const __half* __restrict__ feat16,
                                              const int* __restrict__ start,
                                              const float* __restrict__ h,
                                              float* __restrict__ X,
                                              short* __restrict__ Xh,
                                              short* __restrict__ Xl, int N) {
    __shared__ float accs[4 * D];
    __shared__ float ms[4], ls[4];
    int g = blockIdx.x;
    int t = threadIdx.x;
    int lane = t & 63, wave = t >> 6;
    // publish h into q_star row g (block g owns row g -> race-free)
    float hv = h[(size_t)g * D + t];
    {
        size_t ox = (size_t)g * K2 + t;
        X[ox] = hv;
        short hi = f2bf(hv);
        Xh[ox] = hi;
        Xl[ox] = f2bf(hv - bfs2f(hi));
    }
    int s = start[g], e = start[g + 1];
    s = max(0, min(s, N)); e = max(s, min(e, N));
    int cnt = e - s;
    if (cnt <= 0) {
        size_t ox = (size_t)g * K2 + D + t;
        X[ox] = 0.f; Xh[ox] = 0; Xl[ox] = 0;
        return;
    }
    const float NEG = -3.0e38f;
    float4v q = *(const float4v*)(h + (size_t)g * D + lane * 4);
    float m = NEG, l = 0.f;
    float4v acc = {0.f, 0.f, 0.f, 0.f};

    for (int n0 = wave * 4; n0 < cnt; n0 += 16) {
        uint2 raw[4];
#pragma unroll
        for (int r = 0; r < 4; r++) {
            int idx = n0 + r;
            int ci = (idx < cnt) ? (s + idx) : s;     // clamp: no OOB read
            raw[r] = *((const uint2*)(feat16 + (size_t)ci * D) + lane);
        }
        float4v rows[4];
        float ev[4];
#pragma unroll
        for (int r = 0; r < 4; r++) {
            union { uint2 u; __half2 h2[2]; } cv; cv.u = raw[r];
            float2 f01 = __half22float2(cv.h2[0]);
            float2 f23 = __half22float2(cv.h2[1]);
            rows[r].x = f01.x; rows[r].y = f01.y; rows[r].z = f23.x; rows[r].w = f23.y;
            ev[r] = rows[r].x * q.x + rows[r].y * q.y + rows[r].z * q.z + rows[r].w * q.w;
        }
        // full-wave dot reduction on the VALU (DPP), no DS traffic
#pragma unroll
        for (int r = 0; r < 4; r++) ev[r] = wave_sum64(ev[r]);
        float mnew = m;
#pragma unroll
        for (int r = 0; r < 4; r++) {
            if (n0 + r >= cnt) ev[r] = NEG;
            mnew = fmaxf(mnew, ev[r]);
        }
        float alpha = __expf(m - mnew);
        float w[4];
        float wsum = 0.f;
#pragma unroll
        for (int r = 0; r < 4; r++) {
            w[r] = (n0 + r < cnt) ? __expf(ev[r] - mnew) : 0.f;
            wsum += w[r];
        }
        l = l * alpha + wsum;
        acc.x *= alpha; acc.y *= alpha; acc.z *= alpha; acc.w *= alpha;
#pragma unroll
        for (int r = 0; r < 4; r++) {
            acc.x += w[r] * rows[r].x;
            acc.y += w[r] * rows[r].y;
            acc.z += w[r] * rows[r].z;
            acc.w += w[r] * rows[r].w;
        }
        m = mnew;
    }

    // merge 4 waves via LDS (one-time)
    *((float4v*)(accs + wave * D + lane * 4)) = acc;
    if (lane == 0) { ms[wave] = m; ls[wave] = l; }
    __syncthreads();
    float mt = fmaxf(fmaxf(ms[0], ms[1]), fmaxf(ms[2], ms[3]));
    float s0 = __expf(ms[0] - mt), s1 = __expf(ms[1] - mt);
    float s2 = __expf(ms[2] - mt), s3 = __expf(ms[3] - mt);
    float lt = ls[0] * s0 + ls[1] * s1 + ls[2] * s2 + ls[3] * s3;
    float val = (accs[t] * s0 + accs[D + t] * s1
               + accs[2 * D + t] * s2 + accs[3 * D + t] * s3) / lt;
    size_t ox = (size_t)g * K2 + D + t;
    X[ox] = val;
    short hi = f2bf(val);
    Xh[ox] = hi;
    Xl[ox] = f2bf(val - bfs2f(hi));
}

extern "C" void kernel_launch(void* const* d_in, const int* in_sizes, int n_in,
                              void* d_out, int out_size, void* d_ws, size_t ws_size,
                              hipStream_t stream) {
    const float* feat = (const float*)d_in[0];
    const float* Wih  = (const float*)d_in[1];
    const float* Whh  = (const float*)d_in[2];
    const float* bih  = (const float*)d_in[3];
    const float* bhh  = (const float*)d_in[4];
    const int*   seg  = (const int*)d_in[5];
    const int N = in_sizes[5];
    const int B = out_size / K2;   // 1024
    const int total = N * D;       // 51.2M, multiple of 8

    // ws: [c 1MB | h 1MB | Xh 1MB | Xl 1MB | Wch 1MB | Wcl 1MB | bsum | start]
    // then feat16 at 16MB offset (102.4 MB)
    char* ws = (char*)d_ws;
    size_t szC = (size_t)B * D * sizeof(float);            // 1 MB
    float* c   = (float*)ws;
    float* h   = (float*)(ws + szC);
    short* Xh  = (short*)(ws + 2 * szC);
    short* Xl  = (short*)(ws + 2 * szC + (size_t)B * K2 * sizeof(short));
    short* Wch = (short*)(ws + 2 * szC + 2 * (size_t)B * K2 * sizeof(short));
    short* Wcl = (short*)((char*)Wch + (size_t)G4 * K2 * sizeof(short));
    float* bsum = (float*)((char*)Wcl + (size_t)G4 * K2 * sizeof(short));
    int*   start = (int*)((char*)bsum + (size_t)G4 * sizeof(float));
    __half* feat16 = (__half*)(ws + (size_t)16 * 1024 * 1024);

    float* X = (float*)d_out;      // q_star [B, 2D] fp32

    // zero c | h | Xh | Xl (contiguous 4 MB)
    hipMemsetAsync(ws, 0, 2 * szC + 2 * (size_t)B * K2 * sizeof(short), stream);
    k_cvt<<<8192, 256, 0, stream>>>(feat, feat16, total);
    k_prep<<<(G4 * K2 + 255) / 256, 256, 0, stream>>>(Wih, Whh, bih, bhh, Wch, Wcl, bsum);
    k_bounds<<<(B + 1 + 255) / 256, 256, 0, stream>>>(seg, N, B, start);

    for (int it = 0; it < 6; it++) {
        k_gemm_lstm<<<dim3(B / 16, 4), 256, 0, stream>>>(Xh, Xl, Wch, Wcl, bsum, c, h);
        k_attn<<<B, 256, 0, stream>>>(feat16, start, h, X, Xh, Xl, N);
    }
}